// Round 18
// baseline (380.533 us; speedup 1.0000x reference)
//
#include <hip/hip_runtime.h>

#define NB   256
#define NT   1024
#define PRPT 8
#define TT   (NB * NT)   // 262144 threads * 8 float4 (2 rows each); N2=2,000,000 < 8*TT
#define NHUB 8

typedef unsigned long long ull;
typedef float f32x2 __attribute__((ext_vector_type(2)));

struct alignas(128) Slot { double s[4]; double pad[12]; };   // one 128B line

__device__ __forceinline__ float ex2(float x) { return __builtin_amdgcn_exp2f(x); }

__device__ __forceinline__ float rcp_acc(float d) {
  float r = __builtin_amdgcn_rcpf(d);
  return r * __builtin_fmaf(-d, r, 2.0f);          // 1 NR step (final sigmoid only)
}
__device__ __forceinline__ float div_acc(float n, float d, float r) {
  float q = n * r;
  float rho = __builtin_fmaf(-q, d, n);
  return __builtin_fmaf(rho, r, q);
}

// ---- packed f32 (VOP3P dual-issue). IEEE-identical per lane to scalar ops. ----
__device__ __forceinline__ f32x2 pk_fma(f32x2 a, f32x2 b, f32x2 c) {
  f32x2 d;
  asm("v_pk_fma_f32 %0, %1, %2, %3" : "=v"(d) : "v"(a), "v"(b), "v"(c));
  return d;
}
__device__ __forceinline__ f32x2 pk_add(f32x2 a, f32x2 b) {
  f32x2 d;
  asm("v_pk_add_f32 %0, %1, %2" : "=v"(d) : "v"(a), "v"(b));
  return d;
}
__device__ __forceinline__ f32x2 pk_mul(f32x2 a, f32x2 b) {
  f32x2 d;
  asm("v_pk_mul_f32 %0, %1, %2" : "=v"(d) : "v"(a), "v"(b));
  return d;
}

__device__ __forceinline__ float sigm(double uo) {
  const double C1 = 1.4426950408889634074;
  float w = (float)(-uo * C1);
  w = fminf(fmaxf(w, -60.0f), 60.0f);
  float e = ex2(w);
  float d = 1.0f + e;
  float r = rcp_acc(d);
  return div_acc(1.0f, d, r);
}

// 8-mirrored-hub barrier + stats exchange (round-12/17 proven protocol, verbatim).
__device__ __forceinline__ void layer_sync(
    int l, double s0, double s1, double s2, double s3,
    Slot* __restrict__ slot, Slot* __restrict__ coef,
    float gmv0, float gmv1, float btv0, float btv1, double dn,
    double& P0, double& P1, double& Q0, double& Q1)
{
  __shared__ double lr[NT / 64][4];
  __shared__ double lg[4][4];
  __shared__ double lc[4];
  const int lane = threadIdx.x & 63, wave = threadIdx.x >> 6;
  const ull pbit = (ull)((~((unsigned)l >> 1)) & 1u);   // generation parity for buffer l&1

#pragma unroll
  for (int off = 32; off > 0; off >>= 1) {
    s0 += __shfl_down(s0, off, 64);
    s1 += __shfl_down(s1, off, 64);
    s2 += __shfl_down(s2, off, 64);
    s3 += __shfl_down(s3, off, 64);
  }
  if (lane == 0) { lr[wave][0] = s0; lr[wave][1] = s1; lr[wave][2] = s2; lr[wave][3] = s3; }
  __syncthreads();

  Slot* sb = slot + (size_t)(l & 1) * NB;
  if (threadIdx.x < NT / 64) {
    double a0 = lr[threadIdx.x][0], a1 = lr[threadIdx.x][1];
    double a2 = lr[threadIdx.x][2], a3 = lr[threadIdx.x][3];
#pragma unroll
    for (int off = 8; off > 0; off >>= 1) {
      a0 += __shfl_down(a0, off, 64);
      a1 += __shfl_down(a1, off, 64);
      a2 += __shfl_down(a2, off, 64);
      a3 += __shfl_down(a3, off, 64);
    }
    if (threadIdx.x == 0) {
      ull* my = (ull*)(sb + blockIdx.x)->s;
      __hip_atomic_store(my + 0, (__double_as_longlong(a0) & ~1ull) | pbit,
                         __ATOMIC_RELAXED, __HIP_MEMORY_SCOPE_AGENT);
      __hip_atomic_store(my + 1, (__double_as_longlong(a1) & ~1ull) | pbit,
                         __ATOMIC_RELAXED, __HIP_MEMORY_SCOPE_AGENT);
      __hip_atomic_store(my + 2, (__double_as_longlong(a2) & ~1ull) | pbit,
                         __ATOMIC_RELAXED, __HIP_MEMORY_SCOPE_AGENT);
      __hip_atomic_store(my + 3, (__double_as_longlong(a3) & ~1ull) | pbit,
                         __ATOMIC_RELAXED, __HIP_MEMORY_SCOPE_AGENT);
    }
  }

  if (blockIdx.x < NHUB) {
    if (threadIdx.x < NB) {
      ull* sl = (ull*)(sb + threadIdx.x)->s;
      ull v0, v1, v2, v3;
      for (;;) {
        v0 = __hip_atomic_load(sl + 0, __ATOMIC_RELAXED, __HIP_MEMORY_SCOPE_AGENT);
        v1 = __hip_atomic_load(sl + 1, __ATOMIC_RELAXED, __HIP_MEMORY_SCOPE_AGENT);
        v2 = __hip_atomic_load(sl + 2, __ATOMIC_RELAXED, __HIP_MEMORY_SCOPE_AGENT);
        v3 = __hip_atomic_load(sl + 3, __ATOMIC_RELAXED, __HIP_MEMORY_SCOPE_AGENT);
        if ((((v0 & v1 & v2 & v3) ^ pbit) & 1ull) == 0ull &&
            (((v0 | v1 | v2 | v3) ^ pbit) & 1ull) == 0ull) break;
        __builtin_amdgcn_s_sleep(1);
      }
      double g0 = __longlong_as_double((long long)v0);
      double g1 = __longlong_as_double((long long)v1);
      double g2 = __longlong_as_double((long long)v2);
      double g3 = __longlong_as_double((long long)v3);
#pragma unroll
      for (int off = 32; off > 0; off >>= 1) {
        g0 += __shfl_down(g0, off, 64);
        g1 += __shfl_down(g1, off, 64);
        g2 += __shfl_down(g2, off, 64);
        g3 += __shfl_down(g3, off, 64);
      }
      if (lane == 0) { lg[wave][0] = g0; lg[wave][1] = g1; lg[wave][2] = g2; lg[wave][3] = g3; }
    }
    __syncthreads();
    if (threadIdx.x == 0) {
      const double t0 = lg[0][0] + lg[1][0] + lg[2][0] + lg[3][0];
      const double t1 = lg[0][1] + lg[1][1] + lg[2][1] + lg[3][1];
      const double t2 = lg[0][2] + lg[1][2] + lg[2][2] + lg[3][2];
      const double t3 = lg[0][3] + lg[1][3] + lg[2][3] + lg[3][3];
      const double m0 = t0 * dn, m1 = t1 * dn;
      const double v0 = fma(-m0, m0, t2 * dn);
      const double v1 = fma(-m1, m1, t3 * dn);
      const double rs0 = 1.0 / sqrt(v0 + 1e-5);
      const double rs1 = 1.0 / sqrt(v1 + 1e-5);
      const double A0 = (double)gmv0 * rs0, A1 = (double)gmv1 * rs1;
      const double C2 = 2.8853900817779268147;     // 2*log2(e)
      const ull w0 = (__double_as_longlong(A0 * C2) & ~1ull) | pbit;
      const ull w1 = (__double_as_longlong(A1 * C2) & ~1ull) | pbit;
      const ull w2 = (__double_as_longlong(((double)btv0 - m0 * A0) * C2) & ~1ull) | pbit;
      const ull w3 = (__double_as_longlong(((double)btv1 - m1 * A1) * C2) & ~1ull) | pbit;
      ull* cl = (ull*)(coef + (size_t)(l & 1) * NHUB + blockIdx.x)->s;
      __hip_atomic_store(cl + 0, w0, __ATOMIC_RELAXED, __HIP_MEMORY_SCOPE_AGENT);
      __hip_atomic_store(cl + 1, w1, __ATOMIC_RELAXED, __HIP_MEMORY_SCOPE_AGENT);
      __hip_atomic_store(cl + 2, w2, __ATOMIC_RELAXED, __HIP_MEMORY_SCOPE_AGENT);
      __hip_atomic_store(cl + 3, w3, __ATOMIC_RELAXED, __HIP_MEMORY_SCOPE_AGENT);
      lc[0] = __longlong_as_double((long long)w0);
      lc[1] = __longlong_as_double((long long)w1);
      lc[2] = __longlong_as_double((long long)w2);
      lc[3] = __longlong_as_double((long long)w3);
    }
  } else {
    if (threadIdx.x == 0) {
      ull* cl = (ull*)(coef + (size_t)(l & 1) * NHUB + (blockIdx.x & (NHUB - 1)))->s;
      ull v0, v1, v2, v3;
      for (;;) {
        v0 = __hip_atomic_load(cl + 0, __ATOMIC_RELAXED, __HIP_MEMORY_SCOPE_AGENT);
        v1 = __hip_atomic_load(cl + 1, __ATOMIC_RELAXED, __HIP_MEMORY_SCOPE_AGENT);
        v2 = __hip_atomic_load(cl + 2, __ATOMIC_RELAXED, __HIP_MEMORY_SCOPE_AGENT);
        v3 = __hip_atomic_load(cl + 3, __ATOMIC_RELAXED, __HIP_MEMORY_SCOPE_AGENT);
        if ((((v0 & v1 & v2 & v3) ^ pbit) & 1ull) == 0ull &&
            (((v0 | v1 | v2 | v3) ^ pbit) & 1ull) == 0ull) break;
      }
      lc[0] = __longlong_as_double((long long)v0);
      lc[1] = __longlong_as_double((long long)v1);
      lc[2] = __longlong_as_double((long long)v2);
      lc[3] = __longlong_as_double((long long)v3);
    }
  }
  __syncthreads();
  P0 = lc[0]; P1 = lc[1]; Q0 = lc[2]; Q1 = lc[3];
}

__global__ __launch_bounds__(NT, 4) void fraud_persist(
    const float4* __restrict__ x, const float* __restrict__ W,
    const float* __restrict__ b, const float* __restrict__ gm,
    const float* __restrict__ bt, const float* __restrict__ sc,
    const float* __restrict__ sh, const float* __restrict__ Wf,
    const float* __restrict__ bf, float2* __restrict__ out,
    Slot* __restrict__ slot, Slot* __restrict__ coef, int N2, int L)
{
  const int tid = blockIdx.x * NT + threadIdx.x;
  const bool in8 = (tid + 7 * TT) < N2;            // r=0..6 provably in-bounds
  // channel-paired activation layout: ya[r]=(ch0 row0, ch0 row1), yb[r]=(ch1 ...)
  f32x2 ya[PRPT], yb[PRPT];
  f32x2 SA = {0.f, 0.f}, SB = {0.f, 0.f}, SA2 = {0.f, 0.f}, SB2 = {0.f, 0.f};

  // ---- pass 0: y0 = W0 x + b0 (packed f32) + packed partial stats ----
  {
    const f32x2 vw00 = {W[0], W[0]}, vw01 = {W[1], W[1]};
    const f32x2 vw10 = {W[2], W[2]}, vw11 = {W[3], W[3]};
    const f32x2 vb0 = {b[0], b[0]}, vb1 = {b[1], b[1]};
#pragma unroll
    for (int r = 0; r < PRPT - 1; ++r) {
      const float4 p = x[tid + r * TT];
      const f32x2 pX = {p.x, p.z}, pY = {p.y, p.w};
      const f32x2 a = pk_fma(pX, vw00, pk_fma(pY, vw01, vb0));
      const f32x2 c = pk_fma(pX, vw10, pk_fma(pY, vw11, vb1));
      ya[r] = a; yb[r] = c;
      SA = pk_add(SA, a); SA2 = pk_fma(a, a, SA2);
      SB = pk_add(SB, c); SB2 = pk_fma(c, c, SB2);
    }
    const float4 p = in8 ? x[tid + 7 * TT] : make_float4(0.f, 0.f, 0.f, 0.f);
    const f32x2 pX = {p.x, p.z}, pY = {p.y, p.w};
    const f32x2 a = pk_fma(pX, vw00, pk_fma(pY, vw01, vb0));
    const f32x2 c = pk_fma(pX, vw10, pk_fma(pY, vw11, vb1));
    ya[7] = a; yb[7] = c;
    if (in8) {
      SA = pk_add(SA, a); SA2 = pk_fma(a, a, SA2);
      SB = pk_add(SB, c); SB2 = pk_fma(c, c, SB2);
    }
  }
  const double dn = 0.5 / (double)N2;              // 1/N

  // software-pipelined params (load before the barrier wait)
  float gmv0 = gm[0], gmv1 = gm[1], btv0 = bt[0], btv1 = bt[1];
  float sc0 = sc[0], sh0 = sh[0], sc1 = sc[1], sh1 = sh[1];
  float w00 = W[4], w01 = W[5], w10 = W[6], w11 = W[7];
  float bb0 = b[2], bb1 = b[3];

  double P0, P1, Q0, Q1;
  layer_sync(0, (double)(SA.x + SA.y), (double)(SB.x + SB.y),
             (double)(SA2.x + SA2.y), (double)(SB2.x + SB2.y),
             slot, coef, gmv0, gmv1, btv0, btv1, dn, P0, P1, Q0, Q1);

  const f32x2 vm1 = {-1.f, -1.f}, vp1 = {1.f, 1.f};

  for (int l = 0; l < L; ++l) {
    const bool last = (l == L - 1);

    // affine fold: a = W(sc*t+sh)+b == F*t + G (f64 fold, f32 broadcast pairs)
    f32x2 vF00, vF01, vF10, vF11, vG0, vG1;
    double FD0 = 0.0, FD1 = 0.0, GD = 0.0;
    if (!last) {
      const float F00 = (float)((double)w00 * (double)sc0);
      const float F01 = (float)((double)w01 * (double)sc1);
      const float F10 = (float)((double)w10 * (double)sc0);
      const float F11 = (float)((double)w11 * (double)sc1);
      const float G0  = (float)((double)bb0 + (double)w00 * (double)sh0 + (double)w01 * (double)sh1);
      const float G1  = (float)((double)bb1 + (double)w10 * (double)sh0 + (double)w11 * (double)sh1);
      vF00 = (f32x2){F00, F00}; vF01 = (f32x2){F01, F01};
      vF10 = (f32x2){F10, F10}; vF11 = (f32x2){F11, F11};
      vG0 = (f32x2){G0, G0}; vG1 = (f32x2){G1, G1};
    } else {
      vF00 = vF01 = vF10 = vF11 = vG0 = vG1 = (f32x2){0.f, 0.f};
      FD0 = (double)w00 * (double)sc0;
      FD1 = (double)w01 * (double)sc1;
      GD  = (double)bb0 + (double)w00 * (double)sh0 + (double)w01 * (double)sh1;
    }

    SA = (f32x2){0.f, 0.f}; SB = (f32x2){0.f, 0.f};
    SA2 = (f32x2){0.f, 0.f}; SB2 = (f32x2){0.f, 0.f};
#pragma unroll
    for (int r = 0; r < PRPT; ++r) {
      // tanh (u-path f64 per element; packed f32 elsewhere; bit-identical ops)
      const f32x2 av = ya[r], bv = yb[r];
      const double u0 = fma((double)av.x, P0, Q0);
      const double u1 = fma((double)av.y, P0, Q0);
      const double v0 = fma((double)bv.x, P1, Q1);
      const double v1 = fma((double)bv.y, P1, Q1);
      const f32x2 eA = {ex2((float)u0), ex2((float)u1)};
      const f32x2 eB = {ex2((float)v0), ex2((float)v1)};
      const f32x2 nA = pk_add(eA, vm1), dA = pk_add(eA, vp1);
      const f32x2 nB = pk_add(eB, vm1), dB = pk_add(eB, vp1);
      const f32x2 rA = {__builtin_amdgcn_rcpf(dA.x), __builtin_amdgcn_rcpf(dA.y)};
      const f32x2 rB = {__builtin_amdgcn_rcpf(dB.x), __builtin_amdgcn_rcpf(dB.y)};
      const f32x2 tA = pk_mul(nA, rA), tB = pk_mul(nB, rB);
      const bool ok = (r < 7) || in8;
      if (!last) {
        const f32x2 na = pk_fma(tA, vF00, pk_fma(tB, vF01, vG0));
        const f32x2 nb = pk_fma(tA, vF10, pk_fma(tB, vF11, vG1));
        ya[r] = na; yb[r] = nb;
        if (ok) {
          SA = pk_add(SA, na); SA2 = pk_fma(na, na, SA2);
          SB = pk_add(SB, nb); SB2 = pk_fma(nb, nb, SB2);
        }
      } else if (ok) {
        const double uo0 = fma((double)tA.x, FD0, fma((double)tB.x, FD1, GD));
        const double uo1 = fma((double)tA.y, FD0, fma((double)tB.y, FD1, GD));
        out[tid + r * TT] = make_float2(sigm(uo0), sigm(uo1));
      }
    }
    if (!last) {
      const int n = l + 1;
      gmv0 = gm[2 * n]; gmv1 = gm[2 * n + 1];
      btv0 = bt[2 * n]; btv1 = bt[2 * n + 1];
      sc0 = sc[2 * n]; sh0 = sh[2 * n];
      sc1 = sc[2 * n + 1]; sh1 = sh[2 * n + 1];
      if (n < L - 1) {
        w00 = W[4 * n + 4]; w01 = W[4 * n + 5]; w10 = W[4 * n + 6]; w11 = W[4 * n + 7];
        bb0 = b[2 * n + 2]; bb1 = b[2 * n + 3];
      } else {
        w00 = Wf[0]; w01 = Wf[1]; w10 = 0.0f; w11 = 0.0f; bb0 = bf[0]; bb1 = 0.0f;
      }
      layer_sync(n, (double)(SA.x + SA.y), (double)(SB.x + SB.y),
                 (double)(SA2.x + SA2.y), (double)(SB2.x + SB2.y),
                 slot, coef, gmv0, gmv1, btv0, btv1, dn, P0, P1, Q0, Q1);
    }
  }
}

extern "C" void kernel_launch(void* const* d_in, const int* in_sizes, int n_in,
                              void* d_out, int out_size, void* d_ws, size_t ws_size,
                              hipStream_t stream) {
  const float* x  = (const float*)d_in[0];
  const float* W  = (const float*)d_in[1];
  const float* b  = (const float*)d_in[2];
  const float* gm = (const float*)d_in[3];
  const float* bt = (const float*)d_in[4];
  const float* sc = (const float*)d_in[5];
  const float* sh = (const float*)d_in[6];
  const float* Wf = (const float*)d_in[7];
  const float* bf = (const float*)d_in[8];
  const int N  = in_sizes[0] / 2;
  const int L  = in_sizes[1] / 4;   // 48
  const int N2 = N / 2;             // float4 count (2 rows each)

  char* wsb = (char*)d_ws;
  Slot* coef = (Slot*)wsb;                 // 2 parity x 8 hub-mirrored coef lines
  Slot* slot = (Slot*)(wsb + 4096);        // 2 (parity) * NB slots * 128B = 64KB

  // zero everything: LSB=0 != first expected parity 1 for both buffers
  (void)hipMemsetAsync(d_ws, 0, 4096 + 2 * NB * sizeof(Slot), stream);

  fraud_persist<<<NB, NT, 0, stream>>>(
      (const float4*)x, W, b, gm, bt, sc, sh, Wf, bf,
      (float2*)d_out, slot, coef, N2, L);
}